// Round 1
// baseline (480.515 us; speedup 1.0000x reference)
//
#include <hip/hip_runtime.h>
#include <hip/hip_cooperative_groups.h>
#include <math.h>

namespace cg = cooperative_groups;

// V=50000 D=128 H=256 C=128 R=7 B=1024 T=128
// Full linear fold: c[b] = sum_{p<16} G^s_p x^s_{126-p}[b] + Gx^s x^s_127[b] (s=L,R) + const
// Fused cooperative pipeline (one dispatch, 7 phases, 6 grid.sync):
//   Ph0: prep(E,Gx,dvec)(25) || stack1{S1,A2}(28)
//   Ph1: stack2{S2,S3,A4}(40)
//   Ph2: stack3{S4..7,A8}(64) || fold p0..3 (48)
//   Ph3: stack4{S8..15}(96)   || fold p4..7 (48)
//   Ph4: fold p8..15 (96)     || gemm z=3 (64)   [tc 12..16 ready after Ph2]
//   Ph5: gemm z=0,1,2 (192)
//   Ph6: tail (256) — reduces 8 atomic-free cacc slices (no memset, no atomics)
// Fallback: same phases as 7 ordinary launches if cooperative launch is rejected.

typedef unsigned short ushortx;
typedef unsigned int uintx;
typedef __attribute__((ext_vector_type(8))) short bhalf8;
typedef __attribute__((ext_vector_type(4))) float f32x4;

#define QT_STRIDE 33024      // 129*256

__device__ __forceinline__ float bf2f(ushortx u) {
    union { uintx i; float f; } v; v.i = ((uintx)u) << 16; return v.f;
}
__device__ __forceinline__ ushortx f2bf(float f) {
    union { float f; uintx i; } v; v.f = f;
    uintx b = v.i + 0x7fffu + ((v.i >> 16) & 1u);
    return (ushortx)(b >> 16);
}
__device__ __forceinline__ uintx pack2bf(float a, float b) {
    union { float f; uintx i; } va, vb; va.f = a; vb.f = b;
    return ((va.i + 0x8000u) >> 16) | (((vb.i + 0x8000u) >> 16) << 16);
}
__device__ __forceinline__ int b3p_idx(int side, int tc, int j, int n) {
    return ((side * 17 + tc) * 4 + (j >> 5)) * 4096 + ((j >> 3) & 3) * 1024 + n * 8 + (j & 7);
}

struct TileSm { float As[16][68]; float Bs[16][68]; };
struct GemmSm { ushortx LA[32 * 40]; ushortx LB[4096]; };
struct TailSm { float dsum[128]; float am[4][128]; float logits[4][8]; float lsev[4]; };
union __align__(16) SMemU { TileSm t; GemmSm g; TailSm x; };

// ================= prep body =================
__device__ void prep_body(int b, int tid, TileSm& sm,
                          const float* __restrict__ Wio, const float* __restrict__ bio,
                          const float* __restrict__ Wcpr, const float* __restrict__ bcpr,
                          float* __restrict__ E, ushortx* __restrict__ B3p,
                          float* __restrict__ dvec0) {
    if (b == 24) {
        if (tid < 128) {
            float s = bcpr[tid];
            for (int v = 0; v < 512; ++v) s += Wcpr[tid * 512 + v] * bio[v & 255];
            dvec0[tid] = s;
        }
        return;
    }
    const int tr = tid >> 4, ti = tid & 15;
    float acc[4][4] = {{0.f}};
    const int isE = (b < 16);
    const int side = isE ? (b >> 3) : ((b - 16) >> 2);
    const int tile = isE ? (b & 7) : ((b - 16) & 3);
    const int n0 = isE ? ((tile >> 2) * 64) : ((tile >> 1) * 64);
    const int c0 = isE ? ((tile & 3) * 64) : ((tile & 1) * 64);
    const int wofs = isE ? 128 : 0;
    for (int u0 = 0; u0 < 256; u0 += 16) {
#pragma unroll
        for (int p = 0; p < 4; ++p) {
            int e = p * 256 + tid;
            { int rr = e >> 4, kk = e & 15;
              sm.As[kk][rr] = Wcpr[(n0 + rr) * 512 + side * 256 + u0 + kk]; }
            { int ii = e & 63, kk = e >> 6;
              sm.Bs[kk][ii] = Wio[(u0 + kk) * 384 + wofs + c0 + ii]; }
        }
        __syncthreads();
#pragma unroll
        for (int kk = 0; kk < 16; ++kk) {
            float4 a4 = *(const float4*)&sm.As[kk][tr * 4];
            float4 b4 = *(const float4*)&sm.Bs[kk][ti * 4];
            float av[4] = {a4.x, a4.y, a4.z, a4.w};
            float bv[4] = {b4.x, b4.y, b4.z, b4.w};
#pragma unroll
            for (int x = 0; x < 4; ++x)
#pragma unroll
                for (int y = 0; y < 4; ++y) acc[x][y] += av[x] * bv[y];
        }
        __syncthreads();
    }
    if (isE) {
#pragma unroll
        for (int x = 0; x < 4; ++x) {
            float4 o = make_float4(acc[x][0], acc[x][1], acc[x][2], acc[x][3]);
            *(float4*)&E[side * 32768 + (n0 + tr * 4 + x) * 256 + c0 + ti * 4] = o;
        }
    } else {
#pragma unroll
        for (int x = 0; x < 4; ++x)
#pragma unroll
            for (int y = 0; y < 4; ++y)
                B3p[b3p_idx(side, 16, c0 + ti * 4 + y, n0 + tr * 4 + x)] = f2bf(acc[x][y]);
    }
}

// ================= stack body =================
__device__ void stack_body(int b, int tid, TileSm& sm,
                           const float* __restrict__ Wih, const float* __restrict__ bih,
                           ushortx* __restrict__ QTbf, const float* __restrict__ Ain,
                           float* __restrict__ Aout, int mpow, int count, int lvl1) {
    const int tr = tid >> 4, ti = tid & 15;
    float acc[4][4] = {{0.f}};
    if (b < count * 12) {
        const int slot = b / 12, rem = b % 12;
        const int i0 = (rem & 3) * 64, r0 = (rem >> 2) * 64;
        for (int k0 = 0; k0 < 256; k0 += 16) {
#pragma unroll
            for (int p = 0; p < 4; ++p) {
                int e = p * 256 + tid;
                int rr = e >> 4, kk = e & 15;
                int r = r0 + rr, k = k0 + kk;
                float av;
                if (slot == 0)
                    av = (r < 128) ? Wih[k * 384 + r] : ((r == 128) ? bih[k] : 0.f);
                else
                    av = (r < 129) ? bf2f(QTbf[slot * QT_STRIDE + r * 256 + k]) : 0.f;
                sm.As[kk][rr] = av;
                int i = i0 + rr;
                sm.Bs[kk][rr] = lvl1 ? Wih[i * 384 + 128 + k] : Ain[i * 256 + k];
            }
            __syncthreads();
#pragma unroll
            for (int kk = 0; kk < 16; ++kk) {
                float4 a4 = *(const float4*)&sm.As[kk][tr * 4];
                float4 b4 = *(const float4*)&sm.Bs[kk][ti * 4];
                float av[4] = {a4.x, a4.y, a4.z, a4.w};
                float bv[4] = {b4.x, b4.y, b4.z, b4.w};
#pragma unroll
                for (int x = 0; x < 4; ++x)
#pragma unroll
                    for (int y = 0; y < 4; ++y) acc[x][y] += av[x] * bv[y];
            }
            __syncthreads();
        }
        ushortx* __restrict__ Cdst = QTbf + (mpow + slot) * QT_STRIDE;
#pragma unroll
        for (int x = 0; x < 4; ++x) {
            int r = r0 + tr * 4 + x;
            if (r < 129)
#pragma unroll
                for (int y = 0; y < 4; ++y)
                    Cdst[r * 256 + i0 + ti * 4 + y] = f2bf(acc[x][y]);
        }
    } else {
        const int b2 = b - count * 12;
        const int s0 = (b2 & 3) * 64, i0 = (b2 >> 2) * 64;
        for (int r0 = 0; r0 < 256; r0 += 16) {
#pragma unroll
            for (int p = 0; p < 4; ++p) {
                int e = p * 256 + tid;
                { int rr = e >> 4, kk = e & 15;
                  int i = i0 + rr, k = r0 + kk;
                  sm.As[kk][rr] = lvl1 ? Wih[i * 384 + 128 + k] : Ain[i * 256 + k]; }
                { int ii = e & 63, kk = e >> 6;
                  int r = r0 + kk, s = s0 + ii;
                  sm.Bs[kk][ii] = lvl1 ? Wih[r * 384 + 128 + s] : Ain[r * 256 + s]; }
            }
            __syncthreads();
#pragma unroll
            for (int kk = 0; kk < 16; ++kk) {
                float4 a4 = *(const float4*)&sm.As[kk][tr * 4];
                float4 b4 = *(const float4*)&sm.Bs[kk][ti * 4];
                float av[4] = {a4.x, a4.y, a4.z, a4.w};
                float bv[4] = {b4.x, b4.y, b4.z, b4.w};
#pragma unroll
                for (int x = 0; x < 4; ++x)
#pragma unroll
                    for (int y = 0; y < 4; ++y) acc[x][y] += av[x] * bv[y];
            }
            __syncthreads();
        }
#pragma unroll
        for (int x = 0; x < 4; ++x) {
            float4 o = make_float4(acc[x][0], acc[x][1], acc[x][2], acc[x][3]);
            *(float4*)&Aout[(i0 + tr * 4 + x) * 256 + s0 + ti * 4] = o;
        }
    }
}

// ================= fold body =================
__device__ void fold_body(int side, int p, int tile, int tid, TileSm& sm,
                          const float* __restrict__ Wih, const float* __restrict__ bih,
                          const ushortx* __restrict__ QTbf, const float* __restrict__ E,
                          ushortx* __restrict__ B3p, float* __restrict__ BiasF) {
    const int n0 = (tile / 3) * 64, r0 = (tile % 3) * 64;
    const int tr = tid >> 4, ti = tid & 15;
    float acc[4][4] = {{0.f}};
    for (int i0 = 0; i0 < 256; i0 += 16) {
#pragma unroll
        for (int q = 0; q < 4; ++q) {
            int e = q * 256 + tid;
            int rr = e >> 4, kk = e & 15;
            sm.As[kk][rr] = E[side * 32768 + (n0 + rr) * 256 + i0 + kk];
            int r = r0 + rr;
            float bv;
            if (p > 0)
                bv = (r < 129) ? bf2f(QTbf[p * QT_STRIDE + r * 256 + i0 + kk]) : 0.f;
            else
                bv = (r < 128) ? Wih[(i0 + kk) * 384 + r] : ((r == 128) ? bih[i0 + kk] : 0.f);
            sm.Bs[kk][rr] = bv;
        }
        __syncthreads();
#pragma unroll
        for (int kk = 0; kk < 16; ++kk) {
            float4 a4 = *(const float4*)&sm.As[kk][tr * 4];
            float4 b4 = *(const float4*)&sm.Bs[kk][ti * 4];
            float av[4] = {a4.x, a4.y, a4.z, a4.w};
            float bv[4] = {b4.x, b4.y, b4.z, b4.w};
#pragma unroll
            for (int x = 0; x < 4; ++x)
#pragma unroll
                for (int y = 0; y < 4; ++y) acc[x][y] += av[x] * bv[y];
        }
        __syncthreads();
    }
    const int tc = 15 - p;
#pragma unroll
    for (int x = 0; x < 4; ++x) {
        int n = n0 + tr * 4 + x;
#pragma unroll
        for (int y = 0; y < 4; ++y) {
            int r = r0 + ti * 4 + y;
            if (r < 128)
                B3p[b3p_idx(side, tc, r, n)] = f2bf(acc[x][y]);
            else if (r == 128)
                BiasF[(side * 16 + p) * 128 + n] = acc[x][y];
        }
    }
}

// ================= gemm body (atomic-free when doAtomic==0) =================
__device__ void gemm_body(int m0, int tc_beg, int tc_end, int tid, GemmSm& sm,
                          const int* __restrict__ lids, const int* __restrict__ rids,
                          const float* __restrict__ emb, const ushortx* __restrict__ B3p,
                          float* __restrict__ cdst, int doAtomic) {
    const int side = (m0 >= 1024);
    const int* __restrict__ idp = side ? rids : lids;
    const int mb = m0 & 1023;
    const int lane = tid & 63, wave = tid >> 6;
    const int wn = wave * 32;
    const int r16 = lane & 15, cq = lane >> 4;
    const int arow = tid >> 3, aseg = tid & 7;
    f32x4 acc[2][2] = {};
    for (int tc = tc_beg; tc < tc_end; ++tc) {
        const int t = (tc < 16) ? (111 + tc) : 127;
        const int id = idp[((mb + arow) << 7) + t];
#pragma unroll 1
        for (int jc = 0; jc < 4; ++jc) {
            __syncthreads();
            const ushortx* __restrict__ bsrc = B3p + (((side * 17 + tc) * 4 + jc) << 12);
            *(uint4*)&sm.LB[tid * 16]     = *(const uint4*)&bsrc[tid * 16];
            *(uint4*)&sm.LB[tid * 16 + 8] = *(const uint4*)&bsrc[tid * 16 + 8];
            const float* __restrict__ asrc = emb + ((size_t)id << 7) + jc * 32 + aseg * 4;
            float4 f0 = *(const float4*)asrc;
            uint2 w;
            w.x = pack2bf(f0.x, f0.y); w.y = pack2bf(f0.z, f0.w);
            *(uint2*)&sm.LA[arow * 40 + aseg * 4] = w;
            __syncthreads();
            bhalf8 af[2], bfr[2];
#pragma unroll
            for (int mm = 0; mm < 2; ++mm)
                af[mm] = *(const bhalf8*)&sm.LA[(mm * 16 + r16) * 40 + cq * 8];
#pragma unroll
            for (int nn = 0; nn < 2; ++nn)
                bfr[nn] = *(const bhalf8*)&sm.LB[cq * 1024 + (wn + nn * 16 + r16) * 8];
#pragma unroll
            for (int mm = 0; mm < 2; ++mm)
#pragma unroll
                for (int nn = 0; nn < 2; ++nn)
                    acc[mm][nn] = __builtin_amdgcn_mfma_f32_16x16x32_bf16(af[mm], bfr[nn], acc[mm][nn], 0, 0, 0);
        }
    }
#pragma unroll
    for (int mm = 0; mm < 2; ++mm)
#pragma unroll
        for (int nn = 0; nn < 2; ++nn)
#pragma unroll
            for (int i = 0; i < 4; ++i) {
                int bq = mb + mm * 16 + cq * 4 + i;
                int n = wn + nn * 16 + r16;
                if (doAtomic) atomicAdd(&cdst[bq * 128 + n], acc[mm][nn][i]);
                else          cdst[bq * 128 + n] = acc[mm][nn][i];
            }
}

// ================= tail body (reduces nsl slices) =================
__device__ void tail_body(int b0, int tid, TailSm& sm,
                          const float* __restrict__ csrc, int nsl,
                          const float* __restrict__ BiasF, const float* __restrict__ dvec0,
                          const float* __restrict__ Wsm, const float* __restrict__ bsm,
                          float* __restrict__ out) {
    if (tid < 128) {
        float s = dvec0[tid];
#pragma unroll
        for (int q = 0; q < 32; ++q) s += BiasF[q * 128 + tid];
        sm.dsum[tid] = s;
    }
    __syncthreads();
    {
        const int rb = tid >> 6, nn = (tid & 63) * 2;
#pragma unroll
        for (int d = 0; d < 2; ++d) {
            float c = sm.dsum[nn + d];
            for (int s = 0; s < nsl; ++s)
                c += csrc[(size_t)s * 131072 + (b0 + rb) * 128 + nn + d];
            sm.am[rb][nn + d] = (c >= 0.f) ? c : 0.01f * c;
        }
    }
    __syncthreads();
    if (tid < 28) {
        int rb = tid / 7, r = tid % 7;
        float s = bsm[r];
        for (int q = 0; q < 128; ++q) s += sm.am[rb][q] * Wsm[r * 128 + q];
        sm.logits[rb][r] = s;
    }
    __syncthreads();
    if (tid < 4) {
        float mx = sm.logits[tid][0];
        for (int r = 1; r < 7; ++r) mx = fmaxf(mx, sm.logits[tid][r]);
        float se = 0.f;
        for (int r = 0; r < 7; ++r) se += expf(sm.logits[tid][r] - mx);
        sm.lsev[tid] = mx + logf(se);
    }
    __syncthreads();
    if (tid < 28) {
        int rb = tid / 7, r = tid % 7;
        out[(b0 + rb) * 7 + r] = sm.logits[rb][r] - sm.lsev[rb];
    }
}

// ================= phase dispatcher (shared by mega + fallback) =================
__device__ void run_phase(int ph, int bx, int tid, SMemU& sm,
                          const int* lids, const int* rids, const float* emb,
                          const float* Wih, const float* bih, const float* Wio,
                          const float* bio, const float* Wcpr, const float* bcpr,
                          const float* Wsm, const float* bsm, float* out, char* base) {
    ushortx* QTbf  = (ushortx*)(base);                 // 16*33024*2
    ushortx* B3p   = (ushortx*)(base + 0x102000);      // 557056*2
    float*   BiasF = (float*)  (base + 0x212000);      // 2*16*128*4
    float*   E     = (float*)  (base + 0x216000);      // 2*128*256*4
    float*   dvec0 = (float*)  (base + 0x256000);      // 512
    float*   A2    = (float*)  (base + 0x258000);
    float*   A4    = (float*)  (base + 0x298000);
    float*   A8    = (float*)  (base + 0x2D8000);
    float*   caccZ = (float*)  (base + 0x318000);      // 8 * 1024*128*4 = 4 MB
    switch (ph) {
    case 0:
        if (bx < 25) prep_body(bx, tid, sm.t, Wio, bio, Wcpr, bcpr, E, B3p, dvec0);
        else if (bx < 53) stack_body(bx - 25, tid, sm.t, Wih, bih, QTbf, nullptr, A2, 1, 1, 1);
        break;
    case 1:
        if (bx < 40) stack_body(bx, tid, sm.t, Wih, bih, QTbf, A2, A4, 2, 2, 0);
        break;
    case 2:
        if (bx < 64) stack_body(bx, tid, sm.t, Wih, bih, QTbf, A4, A8, 4, 4, 0);
        else if (bx < 112) {
            int pp = bx - 64;
            fold_body(pp / 24, (pp % 24) / 6, pp % 6, tid, sm.t, Wih, bih, QTbf, E, B3p, BiasF);
        }
        break;
    case 3:
        if (bx < 96) stack_body(bx, tid, sm.t, Wih, bih, QTbf, A8, nullptr, 8, 8, 0);
        else if (bx < 144) {
            int pp = bx - 96;
            fold_body(pp / 24, 4 + (pp % 24) / 6, pp % 6, tid, sm.t, Wih, bih, QTbf, E, B3p, BiasF);
        }
        break;
    case 4:
        if (bx < 96) {
            fold_body(bx / 48, 8 + (bx % 48) / 6, bx % 6, tid, sm.t, Wih, bih, QTbf, E, B3p, BiasF);
        } else if (bx < 160) {
            int g = bx - 96, m0 = g * 32, side = (m0 >= 1024);
            gemm_body(m0, 12, 17, tid, sm.g, lids, rids, emb, B3p,
                      caccZ + (size_t)(side * 4 + 3) * 131072, 0);
        }
        break;
    case 5:
        if (bx < 192) {
            int z = bx % 3, m0 = (bx / 3) * 32, side = (m0 >= 1024);
            gemm_body(m0, (17 * z) >> 2, (17 * (z + 1)) >> 2, tid, sm.g, lids, rids, emb, B3p,
                      caccZ + (size_t)(side * 4 + z) * 131072, 0);
        }
        break;
    case 6:
        tail_body(bx * 4, tid, sm.x, caccZ, 8, BiasF, dvec0, Wsm, bsm, out);
        break;
    }
}

// ================= cooperative mega-kernel =================
__global__ __launch_bounds__(256, 1) void mega(const int* lids, const int* rids,
                                               const float* emb, const float* Wih,
                                               const float* bih, const float* Wio,
                                               const float* bio, const float* Wcpr,
                                               const float* bcpr, const float* Wsm,
                                               const float* bsm, float* out, char* base) {
    __shared__ SMemU sm;
    cg::grid_group grid = cg::this_grid();
    const int bx = blockIdx.x, tid = threadIdx.x;
    run_phase(0, bx, tid, sm, lids, rids, emb, Wih, bih, Wio, bio, Wcpr, bcpr, Wsm, bsm, out, base);
    grid.sync();
    run_phase(1, bx, tid, sm, lids, rids, emb, Wih, bih, Wio, bio, Wcpr, bcpr, Wsm, bsm, out, base);
    grid.sync();
    run_phase(2, bx, tid, sm, lids, rids, emb, Wih, bih, Wio, bio, Wcpr, bcpr, Wsm, bsm, out, base);
    grid.sync();
    run_phase(3, bx, tid, sm, lids, rids, emb, Wih, bih, Wio, bio, Wcpr, bcpr, Wsm, bsm, out, base);
    grid.sync();
    run_phase(4, bx, tid, sm, lids, rids, emb, Wih, bih, Wio, bio, Wcpr, bcpr, Wsm, bsm, out, base);
    grid.sync();
    run_phase(5, bx, tid, sm, lids, rids, emb, Wih, bih, Wio, bio, Wcpr, bcpr, Wsm, bsm, out, base);
    grid.sync();
    run_phase(6, bx, tid, sm, lids, rids, emb, Wih, bih, Wio, bio, Wcpr, bcpr, Wsm, bsm, out, base);
}

// ================= fallback: one generic phase kernel =================
__global__ __launch_bounds__(256) void phase_k(int ph, const int* lids, const int* rids,
                                               const float* emb, const float* Wih,
                                               const float* bih, const float* Wio,
                                               const float* bio, const float* Wcpr,
                                               const float* bcpr, const float* Wsm,
                                               const float* bsm, float* out, char* base) {
    __shared__ SMemU sm;
    run_phase(ph, blockIdx.x, threadIdx.x, sm, lids, rids, emb, Wih, bih, Wio, bio,
              Wcpr, bcpr, Wsm, bsm, out, base);
}

extern "C" void kernel_launch(void* const* d_in, const int* in_sizes, int n_in,
                              void* d_out, int out_size, void* d_ws, size_t ws_size,
                              hipStream_t stream) {
    const int*   lids = (const int*)  d_in[0];
    const int*   rids = (const int*)  d_in[1];
    const float* emb  = (const float*)d_in[2];
    const float* Wih  = (const float*)d_in[3];
    const float* bih  = (const float*)d_in[4];
    const float* Wio  = (const float*)d_in[5];
    const float* bio  = (const float*)d_in[6];
    const float* Wcpr = (const float*)d_in[7];
    const float* bcpr = (const float*)d_in[8];
    const float* Wsm  = (const float*)d_in[9];
    const float* bsm  = (const float*)d_in[10];
    float* out = (float*)d_out;
    char* base = (char*)d_ws;   // uses 0x318000 + 4 MB = ~7.4 MB of workspace

    void* kargs[] = {(void*)&lids, (void*)&rids, (void*)&emb, (void*)&Wih, (void*)&bih,
                     (void*)&Wio, (void*)&bio, (void*)&Wcpr, (void*)&bcpr, (void*)&Wsm,
                     (void*)&bsm, (void*)&out, (void*)&base};
    hipError_t e = hipLaunchCooperativeKernel((void*)mega, dim3(256), dim3(256), kargs, 0, stream);
    if (e != hipSuccess) {
        (void)hipGetLastError();  // clear sticky error, fall back to 7 plain launches
        static const int grids[7] = {53, 40, 112, 144, 160, 192, 256};
        for (int ph = 0; ph < 7; ++ph)
            phase_k<<<grids[ph], 256, 0, stream>>>(ph, lids, rids, emb, Wih, bih, Wio, bio,
                                                   Wcpr, bcpr, Wsm, bsm, out, base);
    }
}

// Round 2
// 262.602 us; speedup vs baseline: 1.8298x; 1.8298x over previous
//
#include <hip/hip_runtime.h>
#include <math.h>

// V=50000 D=128 H=256 C=128 R=7 B=1024 T=128
// Full linear fold: c[b] = sum_{p<16} G^s_p x^s_{126-p}[b] + Gx^s x^s_127[b] (s=L,R) + const
// 7 stream-ordered launches (no cooperative sync, no atomics, no memset):
//   P0: prep(E,Gx,dvec)(25) || stack1{S1,A2}(28)          grid 53
//   P1: stack2{S2,S3,A4}                                   grid 40
//   P2: stack3{S4..7,A8}(64) || fold p0..3 (48)            grid 112
//   P3: stack4{S8..15}(96)   || fold p4..7 (48)            grid 144
//   P4: fold p8..15 (96)     || gemm z=3 tc12..16 (64)     grid 160
//   P5: gemm z=0,1,2 tc0..11                               grid 192
//   P6: tail — reduce 4 cacc slices x 2 sides              grid 256
// cacc slices: caccZ[z][row(2048)][n(128)] fp32, z=0..3 — unique writer per (z,row).

typedef unsigned short ushortx;
typedef unsigned int uintx;
typedef __attribute__((ext_vector_type(8))) short bhalf8;
typedef __attribute__((ext_vector_type(4))) float f32x4;

#define QT_STRIDE 33024      // 129*256
#define CSL 262144           // 2048*128 floats per slice

__device__ __forceinline__ float bf2f(ushortx u) {
    union { uintx i; float f; } v; v.i = ((uintx)u) << 16; return v.f;
}
__device__ __forceinline__ ushortx f2bf(float f) {
    union { float f; uintx i; } v; v.f = f;
    uintx b = v.i + 0x7fffu + ((v.i >> 16) & 1u);
    return (ushortx)(b >> 16);
}
__device__ __forceinline__ uintx pack2bf(float a, float b) {
    union { float f; uintx i; } va, vb; va.f = a; vb.f = b;
    return ((va.i + 0x8000u) >> 16) | (((vb.i + 0x8000u) >> 16) << 16);
}
__device__ __forceinline__ int b3p_idx(int side, int tc, int j, int n) {
    return ((side * 17 + tc) * 4 + (j >> 5)) * 4096 + ((j >> 3) & 3) * 1024 + n * 8 + (j & 7);
}

struct TileSm { float As[16][68]; float Bs[16][68]; };
struct GemmSm { ushortx LA[32 * 40]; ushortx LB[4096]; };
struct TailSm { float dsum[128]; float am[4][128]; float logits[4][8]; float lsev[4]; };
union __align__(16) SMemU { TileSm t; GemmSm g; TailSm x; };

// ================= prep body =================
__device__ void prep_body(int b, int tid, TileSm& sm,
                          const float* __restrict__ Wio, const float* __restrict__ bio,
                          const float* __restrict__ Wcpr, const float* __restrict__ bcpr,
                          float* __restrict__ E, ushortx* __restrict__ B3p,
                          float* __restrict__ dvec0) {
    if (b == 24) {
        if (tid < 128) {
            float s = bcpr[tid];
            for (int v = 0; v < 512; ++v) s += Wcpr[tid * 512 + v] * bio[v & 255];
            dvec0[tid] = s;
        }
        return;
    }
    const int tr = tid >> 4, ti = tid & 15;
    float acc[4][4] = {{0.f}};
    const int isE = (b < 16);
    const int side = isE ? (b >> 3) : ((b - 16) >> 2);
    const int tile = isE ? (b & 7) : ((b - 16) & 3);
    const int n0 = isE ? ((tile >> 2) * 64) : ((tile >> 1) * 64);
    const int c0 = isE ? ((tile & 3) * 64) : ((tile & 1) * 64);
    const int wofs = isE ? 128 : 0;
    for (int u0 = 0; u0 < 256; u0 += 16) {
#pragma unroll
        for (int p = 0; p < 4; ++p) {
            int e = p * 256 + tid;
            { int rr = e >> 4, kk = e & 15;
              sm.As[kk][rr] = Wcpr[(n0 + rr) * 512 + side * 256 + u0 + kk]; }
            { int ii = e & 63, kk = e >> 6;
              sm.Bs[kk][ii] = Wio[(u0 + kk) * 384 + wofs + c0 + ii]; }
        }
        __syncthreads();
#pragma unroll
        for (int kk = 0; kk < 16; ++kk) {
            float4 a4 = *(const float4*)&sm.As[kk][tr * 4];
            float4 b4 = *(const float4*)&sm.Bs[kk][ti * 4];
            float av[4] = {a4.x, a4.y, a4.z, a4.w};
            float bv[4] = {b4.x, b4.y, b4.z, b4.w};
#pragma unroll
            for (int x = 0; x < 4; ++x)
#pragma unroll
                for (int y = 0; y < 4; ++y) acc[x][y] += av[x] * bv[y];
        }
        __syncthreads();
    }
    if (isE) {
#pragma unroll
        for (int x = 0; x < 4; ++x) {
            float4 o = make_float4(acc[x][0], acc[x][1], acc[x][2], acc[x][3]);
            *(float4*)&E[side * 32768 + (n0 + tr * 4 + x) * 256 + c0 + ti * 4] = o;
        }
    } else {
#pragma unroll
        for (int x = 0; x < 4; ++x)
#pragma unroll
            for (int y = 0; y < 4; ++y)
                B3p[b3p_idx(side, 16, c0 + ti * 4 + y, n0 + tr * 4 + x)] = f2bf(acc[x][y]);
    }
}

// ================= stack body =================
__device__ void stack_body(int b, int tid, TileSm& sm,
                           const float* __restrict__ Wih, const float* __restrict__ bih,
                           ushortx* __restrict__ QTbf, const float* __restrict__ Ain,
                           float* __restrict__ Aout, int mpow, int count, int lvl1) {
    const int tr = tid >> 4, ti = tid & 15;
    float acc[4][4] = {{0.f}};
    if (b < count * 12) {
        const int slot = b / 12, rem = b % 12;
        const int i0 = (rem & 3) * 64, r0 = (rem >> 2) * 64;
        for (int k0 = 0; k0 < 256; k0 += 16) {
#pragma unroll
            for (int p = 0; p < 4; ++p) {
                int e = p * 256 + tid;
                int rr = e >> 4, kk = e & 15;
                int r = r0 + rr, k = k0 + kk;
                float av;
                if (slot == 0)
                    av = (r < 128) ? Wih[k * 384 + r] : ((r == 128) ? bih[k] : 0.f);
                else
                    av = (r < 129) ? bf2f(QTbf[slot * QT_STRIDE + r * 256 + k]) : 0.f;
                sm.As[kk][rr] = av;
                int i = i0 + rr;
                sm.Bs[kk][rr] = lvl1 ? Wih[i * 384 + 128 + k] : Ain[i * 256 + k];
            }
            __syncthreads();
#pragma unroll
            for (int kk = 0; kk < 16; ++kk) {
                float4 a4 = *(const float4*)&sm.As[kk][tr * 4];
                float4 b4 = *(const float4*)&sm.Bs[kk][ti * 4];
                float av[4] = {a4.x, a4.y, a4.z, a4.w};
                float bv[4] = {b4.x, b4.y, b4.z, b4.w};
#pragma unroll
                for (int x = 0; x < 4; ++x)
#pragma unroll
                    for (int y = 0; y < 4; ++y) acc[x][y] += av[x] * bv[y];
            }
            __syncthreads();
        }
        ushortx* __restrict__ Cdst = QTbf + (mpow + slot) * QT_STRIDE;
#pragma unroll
        for (int x = 0; x < 4; ++x) {
            int r = r0 + tr * 4 + x;
            if (r < 129)
#pragma unroll
                for (int y = 0; y < 4; ++y)
                    Cdst[r * 256 + i0 + ti * 4 + y] = f2bf(acc[x][y]);
        }
    } else {
        const int b2 = b - count * 12;
        const int s0 = (b2 & 3) * 64, i0 = (b2 >> 2) * 64;
        for (int r0 = 0; r0 < 256; r0 += 16) {
#pragma unroll
            for (int p = 0; p < 4; ++p) {
                int e = p * 256 + tid;
                { int rr = e >> 4, kk = e & 15;
                  int i = i0 + rr, k = r0 + kk;
                  sm.As[kk][rr] = lvl1 ? Wih[i * 384 + 128 + k] : Ain[i * 256 + k]; }
                { int ii = e & 63, kk = e >> 6;
                  int r = r0 + kk, s = s0 + ii;
                  sm.Bs[kk][ii] = lvl1 ? Wih[r * 384 + 128 + s] : Ain[r * 256 + s]; }
            }
            __syncthreads();
#pragma unroll
            for (int kk = 0; kk < 16; ++kk) {
                float4 a4 = *(const float4*)&sm.As[kk][tr * 4];
                float4 b4 = *(const float4*)&sm.Bs[kk][ti * 4];
                float av[4] = {a4.x, a4.y, a4.z, a4.w};
                float bv[4] = {b4.x, b4.y, b4.z, b4.w};
#pragma unroll
                for (int x = 0; x < 4; ++x)
#pragma unroll
                    for (int y = 0; y < 4; ++y) acc[x][y] += av[x] * bv[y];
            }
            __syncthreads();
        }
#pragma unroll
        for (int x = 0; x < 4; ++x) {
            float4 o = make_float4(acc[x][0], acc[x][1], acc[x][2], acc[x][3]);
            *(float4*)&Aout[(i0 + tr * 4 + x) * 256 + s0 + ti * 4] = o;
        }
    }
}

// ================= fold body =================
__device__ void fold_body(int side, int p, int tile, int tid, TileSm& sm,
                          const float* __restrict__ Wih, const float* __restrict__ bih,
                          const ushortx* __restrict__ QTbf, const float* __restrict__ E,
                          ushortx* __restrict__ B3p, float* __restrict__ BiasF) {
    const int n0 = (tile / 3) * 64, r0 = (tile % 3) * 64;
    const int tr = tid >> 4, ti = tid & 15;
    float acc[4][4] = {{0.f}};
    for (int i0 = 0; i0 < 256; i0 += 16) {
#pragma unroll
        for (int q = 0; q < 4; ++q) {
            int e = q * 256 + tid;
            int rr = e >> 4, kk = e & 15;
            sm.As[kk][rr] = E[side * 32768 + (n0 + rr) * 256 + i0 + kk];
            int r = r0 + rr;
            float bv;
            if (p > 0)
                bv = (r < 129) ? bf2f(QTbf[p * QT_STRIDE + r * 256 + i0 + kk]) : 0.f;
            else
                bv = (r < 128) ? Wih[(i0 + kk) * 384 + r] : ((r == 128) ? bih[i0 + kk] : 0.f);
            sm.Bs[kk][rr] = bv;
        }
        __syncthreads();
#pragma unroll
        for (int kk = 0; kk < 16; ++kk) {
            float4 a4 = *(const float4*)&sm.As[kk][tr * 4];
            float4 b4 = *(const float4*)&sm.Bs[kk][ti * 4];
            float av[4] = {a4.x, a4.y, a4.z, a4.w};
            float bv[4] = {b4.x, b4.y, b4.z, b4.w};
#pragma unroll
            for (int x = 0; x < 4; ++x)
#pragma unroll
                for (int y = 0; y < 4; ++y) acc[x][y] += av[x] * bv[y];
        }
        __syncthreads();
    }
    const int tc = 15 - p;
#pragma unroll
    for (int x = 0; x < 4; ++x) {
        int n = n0 + tr * 4 + x;
#pragma unroll
        for (int y = 0; y < 4; ++y) {
            int r = r0 + ti * 4 + y;
            if (r < 128)
                B3p[b3p_idx(side, tc, r, n)] = f2bf(acc[x][y]);
            else if (r == 128)
                BiasF[(side * 16 + p) * 128 + n] = acc[x][y];
        }
    }
}

// ================= gemm body (plain stores into a private slice) =================
__device__ void gemm_body(int m0, int tc_beg, int tc_end, int tid, GemmSm& sm,
                          const int* __restrict__ lids, const int* __restrict__ rids,
                          const float* __restrict__ emb, const ushortx* __restrict__ B3p,
                          float* __restrict__ cdst) {
    const int side = (m0 >= 1024);
    const int* __restrict__ idp = side ? rids : lids;
    const int mb = m0 & 1023;
    const int lane = tid & 63, wave = tid >> 6;
    const int wn = wave * 32;
    const int r16 = lane & 15, cq = lane >> 4;
    const int arow = tid >> 3, aseg = tid & 7;
    f32x4 acc[2][2] = {};
    for (int tc = tc_beg; tc < tc_end; ++tc) {
        const int t = (tc < 16) ? (111 + tc) : 127;
        const int id = idp[((mb + arow) << 7) + t];
#pragma unroll 1
        for (int jc = 0; jc < 4; ++jc) {
            __syncthreads();
            const ushortx* __restrict__ bsrc = B3p + (((side * 17 + tc) * 4 + jc) << 12);
            *(uint4*)&sm.LB[tid * 16]     = *(const uint4*)&bsrc[tid * 16];
            *(uint4*)&sm.LB[tid * 16 + 8] = *(const uint4*)&bsrc[tid * 16 + 8];
            const float* __restrict__ asrc = emb + ((size_t)id << 7) + jc * 32 + aseg * 4;
            float4 f0 = *(const float4*)asrc;
            uint2 w;
            w.x = pack2bf(f0.x, f0.y); w.y = pack2bf(f0.z, f0.w);
            *(uint2*)&sm.LA[arow * 40 + aseg * 4] = w;
            __syncthreads();
            bhalf8 af[2], bfr[2];
#pragma unroll
            for (int mm = 0; mm < 2; ++mm)
                af[mm] = *(const bhalf8*)&sm.LA[(mm * 16 + r16) * 40 + cq * 8];
#pragma unroll
            for (int nn = 0; nn < 2; ++nn)
                bfr[nn] = *(const bhalf8*)&sm.LB[cq * 1024 + (wn + nn * 16 + r16) * 8];
#pragma unroll
            for (int mm = 0; mm < 2; ++mm)
#pragma unroll
                for (int nn = 0; nn < 2; ++nn)
                    acc[mm][nn] = __builtin_amdgcn_mfma_f32_16x16x32_bf16(af[mm], bfr[nn], acc[mm][nn], 0, 0, 0);
        }
    }
#pragma unroll
    for (int mm = 0; mm < 2; ++mm)
#pragma unroll
        for (int nn = 0; nn < 2; ++nn)
#pragma unroll
            for (int i = 0; i < 4; ++i) {
                int bq = mb + mm * 16 + cq * 4 + i;
                int n = wn + nn * 16 + r16;
                cdst[bq * 128 + n] = acc[mm][nn][i];
            }
}

// ================= tail body: reduce 4 slices x 2 sides =================
__device__ void tail_body(int b0, int tid, TailSm& sm,
                          const float* __restrict__ caccZ,
                          const float* __restrict__ BiasF, const float* __restrict__ dvec0,
                          const float* __restrict__ Wsm, const float* __restrict__ bsm,
                          float* __restrict__ out) {
    if (tid < 128) {
        float s = dvec0[tid];
#pragma unroll
        for (int q = 0; q < 32; ++q) s += BiasF[q * 128 + tid];
        sm.dsum[tid] = s;
    }
    __syncthreads();
    {
        const int rb = tid >> 6, nn = (tid & 63) * 2;
#pragma unroll
        for (int d = 0; d < 2; ++d) {
            float c = sm.dsum[nn + d];
            const int ofs = (b0 + rb) * 128 + nn + d;
#pragma unroll
            for (int s = 0; s < 4; ++s)
                c += caccZ[s * CSL + ofs] + caccZ[s * CSL + 131072 + ofs];
            sm.am[rb][nn + d] = (c >= 0.f) ? c : 0.01f * c;
        }
    }
    __syncthreads();
    if (tid < 28) {
        int rb = tid / 7, r = tid % 7;
        float s = bsm[r];
        for (int q = 0; q < 128; ++q) s += sm.am[rb][q] * Wsm[r * 128 + q];
        sm.logits[rb][r] = s;
    }
    __syncthreads();
    if (tid < 4) {
        float mx = sm.logits[tid][0];
        for (int r = 1; r < 7; ++r) mx = fmaxf(mx, sm.logits[tid][r]);
        float se = 0.f;
        for (int r = 0; r < 7; ++r) se += expf(sm.logits[tid][r] - mx);
        sm.lsev[tid] = mx + logf(se);
    }
    __syncthreads();
    if (tid < 28) {
        int rb = tid / 7, r = tid % 7;
        out[(b0 + rb) * 7 + r] = sm.logits[rb][r] - sm.lsev[rb];
    }
}

// ================= phase kernel =================
__global__ __launch_bounds__(256) void phase_k(int ph, const int* lids, const int* rids,
                                               const float* emb, const float* Wih,
                                               const float* bih, const float* Wio,
                                               const float* bio, const float* Wcpr,
                                               const float* bcpr, const float* Wsm,
                                               const float* bsm, float* out, char* base) {
    __shared__ SMemU sm;
    const int bx = blockIdx.x, tid = threadIdx.x;
    ushortx* QTbf  = (ushortx*)(base);                 // 16*33024*2
    ushortx* B3p   = (ushortx*)(base + 0x102000);      // 557056*2
    float*   BiasF = (float*)  (base + 0x212000);      // 2*16*128*4
    float*   E     = (float*)  (base + 0x216000);      // 2*128*256*4
    float*   dvec0 = (float*)  (base + 0x256000);      // 512
    float*   A2    = (float*)  (base + 0x258000);
    float*   A4    = (float*)  (base + 0x298000);
    float*   A8    = (float*)  (base + 0x2D8000);
    float*   caccZ = (float*)  (base + 0x318000);      // 4 * 2048*128*4 = 4 MB
    switch (ph) {
    case 0:
        if (bx < 25) prep_body(bx, tid, sm.t, Wio, bio, Wcpr, bcpr, E, B3p, dvec0);
        else if (bx < 53) stack_body(bx - 25, tid, sm.t, Wih, bih, QTbf, nullptr, A2, 1, 1, 1);
        break;
    case 1:
        if (bx < 40) stack_body(bx, tid, sm.t, Wih, bih, QTbf, A2, A4, 2, 2, 0);
        break;
    case 2:
        if (bx < 64) stack_body(bx, tid, sm.t, Wih, bih, QTbf, A4, A8, 4, 4, 0);
        else if (bx < 112) {
            int pp = bx - 64;
            fold_body(pp / 24, (pp % 24) / 6, pp % 6, tid, sm.t, Wih, bih, QTbf, E, B3p, BiasF);
        }
        break;
    case 3:
        if (bx < 96) stack_body(bx, tid, sm.t, Wih, bih, QTbf, A8, nullptr, 8, 8, 0);
        else if (bx < 144) {
            int pp = bx - 96;
            fold_body(pp / 24, 4 + (pp % 24) / 6, pp % 6, tid, sm.t, Wih, bih, QTbf, E, B3p, BiasF);
        }
        break;
    case 4:
        if (bx < 96) {
            fold_body(bx / 48, 8 + (bx % 48) / 6, bx % 6, tid, sm.t, Wih, bih, QTbf, E, B3p, BiasF);
        } else if (bx < 160) {
            int g = bx - 96, m0 = g * 32, side = (m0 >= 1024);
            gemm_body(m0, 12, 17, tid, sm.g, lids, rids, emb, B3p,
                      caccZ + (size_t)3 * CSL + side * 131072);
        }
        break;
    case 5:
        if (bx < 192) {
            int z = bx % 3, m0 = (bx / 3) * 32, side = (m0 >= 1024);
            gemm_body(m0, (17 * z) >> 2, (17 * (z + 1)) >> 2, tid, sm.g, lids, rids, emb, B3p,
                      caccZ + (size_t)z * CSL + side * 131072);
        }
        break;
    case 6:
        tail_body(bx * 4, tid, sm.x, caccZ, BiasF, dvec0, Wsm, bsm, out);
        break;
    }
}

extern "C" void kernel_launch(void* const* d_in, const int* in_sizes, int n_in,
                              void* d_out, int out_size, void* d_ws, size_t ws_size,
                              hipStream_t stream) {
    const int*   lids = (const int*)  d_in[0];
    const int*   rids = (const int*)  d_in[1];
    const float* emb  = (const float*)d_in[2];
    const float* Wih  = (const float*)d_in[3];
    const float* bih  = (const float*)d_in[4];
    const float* Wio  = (const float*)d_in[5];
    const float* bio  = (const float*)d_in[6];
    const float* Wcpr = (const float*)d_in[7];
    const float* bcpr = (const float*)d_in[8];
    const float* Wsm  = (const float*)d_in[9];
    const float* bsm  = (const float*)d_in[10];
    float* out = (float*)d_out;
    char* base = (char*)d_ws;   // uses 0x318000 + 4 MB ≈ 7.2 MB of workspace

    static const int grids[7] = {53, 40, 112, 144, 160, 192, 256};
    for (int ph = 0; ph < 7; ++ph)
        phase_k<<<grids[ph], 256, 0, stream>>>(ph, lids, rids, emb, Wih, bih, Wio, bio,
                                               Wcpr, bcpr, Wsm, bsm, out, base);
}

// Round 3
// 237.455 us; speedup vs baseline: 2.0236x; 1.1059x over previous
//
#include <hip/hip_runtime.h>
#include <math.h>

// V=50000 D=128 H=256 C=128 R=7 B=1024 T=128
// Full linear fold: c[b] = sum_{p<16} G^s_p x^s_{126-p}[b] + Gx^s x^s_127[b] (s=L,R) + const
// 7 stream-ordered launches (no cooperative sync, no atomics, no memset):
//   P0: prep(E,Gx,dvec)(25) || stack1{S1,A2}(28)          grid 53
//   P1: stack2{S2,S3,A4}                                   grid 40
//   P2: stack3{S4..7,A8}(64) || fold p0..3 (48)            grid 112
//   P3: stack4{S8..15}(96)   || fold p4..7 (48)            grid 144
//   P4: fold p8..15 (96)     || gemm z=3 tc12..16 (64)     grid 160
//   P5: gemm z=0,1,2 tc0..11                               grid 192
//   P6: tail — reduce 4 cacc slices x 2 sides              grid 256
// R3 body fixes: coalesced Wih-transpose fills (stack slot0 / fold p0),
// gemm B3p direct-to-reg (no LDS, no per-jc sync; 2 syncs per tc),
// gemm A staged as full bf16 row per tc, dvec0 vectorized.

typedef unsigned short ushortx;
typedef unsigned int uintx;
typedef __attribute__((ext_vector_type(8))) short bhalf8;
typedef __attribute__((ext_vector_type(4))) float f32x4;

#define QT_STRIDE 33024      // 129*256
#define CSL 262144           // 2048*128 floats per slice

__device__ __forceinline__ float bf2f(ushortx u) {
    union { uintx i; float f; } v; v.i = ((uintx)u) << 16; return v.f;
}
__device__ __forceinline__ ushortx f2bf(float f) {
    union { float f; uintx i; } v; v.f = f;
    uintx b = v.i + 0x7fffu + ((v.i >> 16) & 1u);
    return (ushortx)(b >> 16);
}
__device__ __forceinline__ uintx pack2bf(float a, float b) {
    union { float f; uintx i; } va, vb; va.f = a; vb.f = b;
    return ((va.i + 0x8000u) >> 16) | (((vb.i + 0x8000u) >> 16) << 16);
}
__device__ __forceinline__ int b3p_idx(int side, int tc, int j, int n) {
    return ((side * 17 + tc) * 4 + (j >> 5)) * 4096 + ((j >> 3) & 3) * 1024 + n * 8 + (j & 7);
}

struct TileSm { float As[16][68]; float Bs[16][68]; };
struct GemmSm { ushortx LA[32 * 136]; };            // 32 rows x 128 bf16, stride 136
struct TailSm { float dsum[128]; float am[4][128]; float logits[4][8]; float lsev[4]; };
union __align__(16) SMemU { TileSm t; GemmSm g; TailSm x; };

// ================= prep body =================
__device__ void prep_body(int b, int tid, TileSm& sm,
                          const float* __restrict__ Wio, const float* __restrict__ bio,
                          const float* __restrict__ Wcpr, const float* __restrict__ bcpr,
                          float* __restrict__ E, ushortx* __restrict__ B3p,
                          float* __restrict__ dvec0) {
    if (b == 24) {
        // dvec0[n] = bcpr[n] + sum_v Wcpr[n][v]*bio[v&255]; bio staged in LDS, float4 row reads
        float* bsh = (float*)sm.As;                  // 256 floats of LDS
        bsh[tid] = bio[tid & 255];
        __syncthreads();
        if (tid < 128) {
            const float* wr = Wcpr + tid * 512;
            float s = bcpr[tid];
#pragma unroll 4
            for (int v = 0; v < 512; v += 4) {
                float4 w = *(const float4*)&wr[v];
                s += w.x * bsh[v & 255] + w.y * bsh[(v + 1) & 255]
                   + w.z * bsh[(v + 2) & 255] + w.w * bsh[(v + 3) & 255];
            }
            dvec0[tid] = s;
        }
        return;
    }
    const int tr = tid >> 4, ti = tid & 15;
    float acc[4][4] = {{0.f}};
    const int isE = (b < 16);
    const int side = isE ? (b >> 3) : ((b - 16) >> 2);
    const int tile = isE ? (b & 7) : ((b - 16) & 3);
    const int n0 = isE ? ((tile >> 2) * 64) : ((tile >> 1) * 64);
    const int c0 = isE ? ((tile & 3) * 64) : ((tile & 1) * 64);
    const int wofs = isE ? 128 : 0;
    for (int u0 = 0; u0 < 256; u0 += 16) {
#pragma unroll
        for (int p = 0; p < 4; ++p) {
            int e = p * 256 + tid;
            { int rr = e >> 4, kk = e & 15;
              sm.As[kk][rr] = Wcpr[(n0 + rr) * 512 + side * 256 + u0 + kk]; }
            { int ii = e & 63, kk = e >> 6;
              sm.Bs[kk][ii] = Wio[(u0 + kk) * 384 + wofs + c0 + ii]; }
        }
        __syncthreads();
#pragma unroll
        for (int kk = 0; kk < 16; ++kk) {
            float4 a4 = *(const float4*)&sm.As[kk][tr * 4];
            float4 b4 = *(const float4*)&sm.Bs[kk][ti * 4];
            float av[4] = {a4.x, a4.y, a4.z, a4.w};
            float bv[4] = {b4.x, b4.y, b4.z, b4.w};
#pragma unroll
            for (int x = 0; x < 4; ++x)
#pragma unroll
                for (int y = 0; y < 4; ++y) acc[x][y] += av[x] * bv[y];
        }
        __syncthreads();
    }
    if (isE) {
#pragma unroll
        for (int x = 0; x < 4; ++x) {
            float4 o = make_float4(acc[x][0], acc[x][1], acc[x][2], acc[x][3]);
            *(float4*)&E[side * 32768 + (n0 + tr * 4 + x) * 256 + c0 + ti * 4] = o;
        }
    } else {
#pragma unroll
        for (int x = 0; x < 4; ++x)
#pragma unroll
            for (int y = 0; y < 4; ++y)
                B3p[b3p_idx(side, 16, c0 + ti * 4 + y, n0 + tr * 4 + x)] = f2bf(acc[x][y]);
    }
}

// ================= stack body =================
__device__ void stack_body(int b, int tid, TileSm& sm,
                           const float* __restrict__ Wih, const float* __restrict__ bih,
                           ushortx* __restrict__ QTbf, const float* __restrict__ Ain,
                           float* __restrict__ Aout, int mpow, int count, int lvl1) {
    const int tr = tid >> 4, ti = tid & 15;
    float acc[4][4] = {{0.f}};
    if (b < count * 12) {
        const int slot = b / 12, rem = b % 12;
        const int i0 = (rem & 3) * 64, r0 = (rem >> 2) * 64;
        for (int k0 = 0; k0 < 256; k0 += 16) {
            // ---- As fill ----
            if (slot == 0) {
                // coalesced transpose-read of [Wx|bih]: thread reads float4 along r
                const int kk = tid >> 4, rq = (tid & 15) * 4;
                const int k = k0 + kk;
                float4 v;
                if (r0 < 128) {
                    v = *(const float4*)&Wih[k * 384 + r0 + rq];
                } else {
                    v.x = (rq == 0) ? bih[k] : 0.f; v.y = 0.f; v.z = 0.f; v.w = 0.f;
                }
                *(float4*)&sm.As[kk][rq] = v;
            } else {
#pragma unroll
                for (int p = 0; p < 4; ++p) {
                    int e = p * 256 + tid;
                    int rr = e >> 4, kk = e & 15;
                    int r = r0 + rr, k = k0 + kk;
                    sm.As[kk][rr] = (r < 129) ? bf2f(QTbf[slot * QT_STRIDE + r * 256 + k]) : 0.f;
                }
            }
            // ---- Bs fill (coalesced along k) ----
#pragma unroll
            for (int p = 0; p < 4; ++p) {
                int e = p * 256 + tid;
                int rr = e >> 4, kk = e & 15;
                int i = i0 + rr, k = k0 + kk;
                sm.Bs[kk][rr] = lvl1 ? Wih[i * 384 + 128 + k] : Ain[i * 256 + k];
            }
            __syncthreads();
#pragma unroll
            for (int kk = 0; kk < 16; ++kk) {
                float4 a4 = *(const float4*)&sm.As[kk][tr * 4];
                float4 b4 = *(const float4*)&sm.Bs[kk][ti * 4];
                float av[4] = {a4.x, a4.y, a4.z, a4.w};
                float bv[4] = {b4.x, b4.y, b4.z, b4.w};
#pragma unroll
                for (int x = 0; x < 4; ++x)
#pragma unroll
                    for (int y = 0; y < 4; ++y) acc[x][y] += av[x] * bv[y];
            }
            __syncthreads();
        }
        ushortx* __restrict__ Cdst = QTbf + (mpow + slot) * QT_STRIDE;
#pragma unroll
        for (int x = 0; x < 4; ++x) {
            int r = r0 + tr * 4 + x;
            if (r < 129)
#pragma unroll
                for (int y = 0; y < 4; ++y)
                    Cdst[r * 256 + i0 + ti * 4 + y] = f2bf(acc[x][y]);
        }
    } else {
        const int b2 = b - count * 12;
        const int s0 = (b2 & 3) * 64, i0 = (b2 >> 2) * 64;
        for (int r0 = 0; r0 < 256; r0 += 16) {
#pragma unroll
            for (int p = 0; p < 4; ++p) {
                int e = p * 256 + tid;
                { int rr = e >> 4, kk = e & 15;
                  int i = i0 + rr, k = r0 + kk;
                  sm.As[kk][rr] = lvl1 ? Wih[i * 384 + 128 + k] : Ain[i * 256 + k]; }
                { int ii = e & 63, kk = e >> 6;
                  int r = r0 + kk, s = s0 + ii;
                  sm.Bs[kk][ii] = lvl1 ? Wih[r * 384 + 128 + s] : Ain[r * 256 + s]; }
            }
            __syncthreads();
#pragma unroll
            for (int kk = 0; kk < 16; ++kk) {
                float4 a4 = *(const float4*)&sm.As[kk][tr * 4];
                float4 b4 = *(const float4*)&sm.Bs[kk][ti * 4];
                float av[4] = {a4.x, a4.y, a4.z, a4.w};
                float bv[4] = {b4.x, b4.y, b4.z, b4.w};
#pragma unroll
                for (int x = 0; x < 4; ++x)
#pragma unroll
                    for (int y = 0; y < 4; ++y) acc[x][y] += av[x] * bv[y];
            }
            __syncthreads();
        }
#pragma unroll
        for (int x = 0; x < 4; ++x) {
            float4 o = make_float4(acc[x][0], acc[x][1], acc[x][2], acc[x][3]);
            *(float4*)&Aout[(i0 + tr * 4 + x) * 256 + s0 + ti * 4] = o;
        }
    }
}

// ================= fold body =================
__device__ void fold_body(int side, int p, int tile, int tid, TileSm& sm,
                          const float* __restrict__ Wih, const float* __restrict__ bih,
                          const ushortx* __restrict__ QTbf, const float* __restrict__ E,
                          ushortx* __restrict__ B3p, float* __restrict__ BiasF) {
    const int n0 = (tile / 3) * 64, r0 = (tile % 3) * 64;
    const int tr = tid >> 4, ti = tid & 15;
    float acc[4][4] = {{0.f}};
    for (int i0 = 0; i0 < 256; i0 += 16) {
        // ---- As fill (coalesced along i) ----
#pragma unroll
        for (int q = 0; q < 4; ++q) {
            int e = q * 256 + tid;
            int rr = e >> 4, kk = e & 15;
            sm.As[kk][rr] = E[side * 32768 + (n0 + rr) * 256 + i0 + kk];
        }
        // ---- Bs fill ----
        if (p > 0) {
#pragma unroll
            for (int q = 0; q < 4; ++q) {
                int e = q * 256 + tid;
                int rr = e >> 4, kk = e & 15;
                int r = r0 + rr;
                sm.Bs[kk][rr] = (r < 129) ? bf2f(QTbf[p * QT_STRIDE + r * 256 + i0 + kk]) : 0.f;
            }
        } else {
            // coalesced transpose-read of [Wx|bih]: float4 along r
            const int kk = tid >> 4, rq = (tid & 15) * 4;
            const int i = i0 + kk;
            float4 v;
            if (r0 < 128) {
                v = *(const float4*)&Wih[i * 384 + r0 + rq];
            } else {
                v.x = (rq == 0) ? bih[i] : 0.f; v.y = 0.f; v.z = 0.f; v.w = 0.f;
            }
            *(float4*)&sm.Bs[kk][rq] = v;
        }
        __syncthreads();
#pragma unroll
        for (int kk = 0; kk < 16; ++kk) {
            float4 a4 = *(const float4*)&sm.As[kk][tr * 4];
            float4 b4 = *(const float4*)&sm.Bs[kk][ti * 4];
            float av[4] = {a4.x, a4.y, a4.z, a4.w};
            float bv[4] = {b4.x, b4.y, b4.z, b4.w};
#pragma unroll
            for (int x = 0; x < 4; ++x)
#pragma unroll
                for (int y = 0; y < 4; ++y) acc[x][y] += av[x] * bv[y];
        }
        __syncthreads();
    }
    const int tc = 15 - p;
#pragma unroll
    for (int x = 0; x < 4; ++x) {
        int n = n0 + tr * 4 + x;
#pragma unroll
        for (int y = 0; y < 4; ++y) {
            int r = r0 + ti * 4 + y;
            if (r < 128)
                B3p[b3p_idx(side, tc, r, n)] = f2bf(acc[x][y]);
            else if (r == 128)
                BiasF[(side * 16 + p) * 128 + n] = acc[x][y];
        }
    }
}

// ================= gemm body: B3p direct-to-reg, A row-staged per tc =================
__device__ void gemm_body(int m0, int tc_beg, int tc_end, int tid, GemmSm& sm,
                          const int* __restrict__ lids, const int* __restrict__ rids,
                          const float* __restrict__ emb, const ushortx* __restrict__ B3p,
                          float* __restrict__ cdst) {
    const int side = (m0 >= 1024);
    const int* __restrict__ idp = side ? rids : lids;
    const int mb = m0 & 1023;
    const int lane = tid & 63, wave = tid >> 6;
    const int wn = wave * 32;
    const int r16 = lane & 15, cq = lane >> 4;
    const int arow = tid >> 3, aseg = tid & 7;
    f32x4 acc[2][2] = {};
#pragma unroll 1
    for (int tc = tc_beg; tc < tc_end; ++tc) {
        const int t = (tc < 16) ? (111 + tc) : 127;
        const int id = idp[((mb + arow) << 7) + t];
        // B: all 4 jc chunks direct from global (L2) to regs — each element used once.
        // coalesced: 16 consecutive lanes (r16) read 16 consecutive 16B segments.
        const ushortx* __restrict__ bbase =
            B3p + (((side * 17 + tc) * 4) << 12) + cq * 1024 + (wn + r16) * 8;
        bhalf8 bfr[4][2];
#pragma unroll
        for (int jc = 0; jc < 4; ++jc) {
#pragma unroll
            for (int nn = 0; nn < 2; ++nn)
                bfr[jc][nn] = *(const bhalf8*)&bbase[jc * 4096 + nn * 128];
        }
        // A: full 128-float row -> bf16 LDS (one stage per tc)
        const float* __restrict__ asrc = emb + ((size_t)id << 7) + aseg * 16;
        float4 f0 = *(const float4*)(asrc);
        float4 f1 = *(const float4*)(asrc + 4);
        float4 f2 = *(const float4*)(asrc + 8);
        float4 f3 = *(const float4*)(asrc + 12);
        uint4 w0, w1;
        w0.x = pack2bf(f0.x, f0.y); w0.y = pack2bf(f0.z, f0.w);
        w0.z = pack2bf(f1.x, f1.y); w0.w = pack2bf(f1.z, f1.w);
        w1.x = pack2bf(f2.x, f2.y); w1.y = pack2bf(f2.z, f2.w);
        w1.z = pack2bf(f3.x, f3.y); w1.w = pack2bf(f3.z, f3.w);
        __syncthreads();   // previous-iteration readers done
        *(uint4*)&sm.LA[arow * 136 + aseg * 16]     = w0;
        *(uint4*)&sm.LA[arow * 136 + aseg * 16 + 8] = w1;
        __syncthreads();
#pragma unroll
        for (int jc = 0; jc < 4; ++jc) {
            bhalf8 af[2];
#pragma unroll
            for (int mm = 0; mm < 2; ++mm)
                af[mm] = *(const bhalf8*)&sm.LA[(mm * 16 + r16) * 136 + jc * 32 + cq * 8];
#pragma unroll
            for (int mm = 0; mm < 2; ++mm)
#pragma unroll
                for (int nn = 0; nn < 2; ++nn)
                    acc[mm][nn] = __builtin_amdgcn_mfma_f32_16x16x32_bf16(af[mm], bfr[jc][nn], acc[mm][nn], 0, 0, 0);
        }
    }
#pragma unroll
    for (int mm = 0; mm < 2; ++mm)
#pragma unroll
        for (int nn = 0; nn < 2; ++nn)
#pragma unroll
            for (int i = 0; i < 4; ++i) {
                int bq = mb + mm * 16 + cq * 4 + i;
                int n = wn + nn * 16 + r16;
                cdst[bq * 128 + n] = acc[mm][nn][i];
            }
}

// ================= tail body: reduce 4 slices x 2 sides =================
__device__ void tail_body(int b0, int tid, TailSm& sm,
                          const float* __restrict__ caccZ,
                          const float* __restrict__ BiasF, const float* __restrict__ dvec0,
                          const float* __restrict__ Wsm, const float* __restrict__ bsm,
                          float* __restrict__ out) {
    if (tid < 128) {
        float s = dvec0[tid];
#pragma unroll
        for (int q = 0; q < 32; ++q) s += BiasF[q * 128 + tid];
        sm.dsum[tid] = s;
    }
    __syncthreads();
    {
        const int rb = tid >> 6, nn = (tid & 63) * 2;
#pragma unroll
        for (int d = 0; d < 2; ++d) {
            float c = sm.dsum[nn + d];
            const int ofs = (b0 + rb) * 128 + nn + d;
#pragma unroll
            for (int s = 0; s < 4; ++s)
                c += caccZ[s * CSL + ofs] + caccZ[s * CSL + 131072 + ofs];
            sm.am[rb][nn + d] = (c >= 0.f) ? c : 0.01f * c;
        }
    }
    __syncthreads();
    if (tid < 28) {
        int rb = tid / 7, r = tid % 7;
        float s = bsm[r];
        for (int q = 0; q < 128; ++q) s += sm.am[rb][q] * Wsm[r * 128 + q];
        sm.logits[rb][r] = s;
    }
    __syncthreads();
    if (tid < 4) {
        float mx = sm.logits[tid][0];
        for (int r = 1; r < 7; ++r) mx = fmaxf(mx, sm.logits[tid][r]);
        float se = 0.f;
        for (int r = 0; r < 7; ++r) se += expf(sm.logits[tid][r] - mx);
        sm.lsev[tid] = mx + logf(se);
    }
    __syncthreads();
    if (tid < 28) {
        int rb = tid / 7, r = tid % 7;
        out[(b0 + rb) * 7 + r] = sm.logits[rb][r] - sm.lsev[rb];
    }
}

// ================= phase kernel =================
__global__ __launch_bounds__(256) void phase_k(int ph, const int* lids, const int* rids,
                                               const float* emb, const float* Wih,
                                               const float* bih, const float* Wio,
                                               const float* bio, const float* Wcpr,
                                               const float* bcpr, const float* Wsm,
                                               const float* bsm, float* out, char* base) {
    __shared__ SMemU sm;
    const int bx = blockIdx.x, tid = threadIdx.x;
    ushortx* QTbf  = (ushortx*)(base);                 // 16*33024*2
    ushortx* B3p   = (ushortx*)(base + 0x102000);      // 557056*2
    float*   BiasF = (float*)  (base + 0x212000);      // 2*16*128*4
    float*   E     = (float*)  (base + 0x216000);      // 2*128*256*4
    float*   dvec0 = (float*)  (base + 0x256000);      // 512
    float*   A2    = (float*)  (base + 0x258000);
    float*   A4    = (float*)  (base + 0x298000);
    float*   A8    = (float*)  (base + 0x2D8000);
    float*   caccZ = (float*)  (base + 0x318000);      // 4 * 2048*128*4 = 4 MB
    switch (ph) {
    case 0:
        if (bx < 25) prep_body(bx, tid, sm.t, Wio, bio, Wcpr, bcpr, E, B3p, dvec0);
        else if (bx < 53) stack_body(bx - 25, tid, sm.t, Wih, bih, QTbf, nullptr, A2, 1, 1, 1);
        break;
    case 1:
        if (bx < 40) stack_body(bx, tid, sm.t, Wih, bih, QTbf, A2, A4, 2, 2, 0);
        break;
    case 2:
        if (bx < 64) stack_body(bx, tid, sm.t, Wih, bih, QTbf, A4, A8, 4, 4, 0);
        else if (bx < 112) {
            int pp = bx - 64;
            fold_body(pp / 24, (pp % 24) / 6, pp % 6, tid, sm.t, Wih, bih, QTbf, E, B3p, BiasF);
        }
        break;
    case 3:
        if (bx < 96) stack_body(bx, tid, sm.t, Wih, bih, QTbf, A8, nullptr, 8, 8, 0);
        else if (bx < 144) {
            int pp = bx - 96;
            fold_body(pp / 24, 4 + (pp % 24) / 6, pp % 6, tid, sm.t, Wih, bih, QTbf, E, B3p, BiasF);
        }
        break;
    case 4:
        if (bx < 96) {
            fold_body(bx / 48, 8 + (bx % 48) / 6, bx % 6, tid, sm.t, Wih, bih, QTbf, E, B3p, BiasF);
        } else if (bx < 160) {
            int g = bx - 96, m0 = g * 32, side = (m0 >= 1024);
            gemm_body(m0, 12, 17, tid, sm.g, lids, rids, emb, B3p,
                      caccZ + (size_t)3 * CSL + side * 131072);
        }
        break;
    case 5:
        if (bx < 192) {
            int z = bx % 3, m0 = (bx / 3) * 32, side = (m0 >= 1024);
            gemm_body(m0, (17 * z) >> 2, (17 * (z + 1)) >> 2, tid, sm.g, lids, rids, emb, B3p,
                      caccZ + (size_t)z * CSL + side * 131072);
        }
        break;
    case 6:
        tail_body(bx * 4, tid, sm.x, caccZ, BiasF, dvec0, Wsm, bsm, out);
        break;
    }
}

extern "C" void kernel_launch(void* const* d_in, const int* in_sizes, int n_in,
                              void* d_out, int out_size, void* d_ws, size_t ws_size,
                              hipStream_t stream) {
    const int*   lids = (const int*)  d_in[0];
    const int*   rids = (const int*)  d_in[1];
    const float* emb  = (const float*)d_in[2];
    const float* Wih  = (const float*)d_in[3];
    const float* bih  = (const float*)d_in[4];
    const float* Wio  = (const float*)d_in[5];
    const float* bio  = (const float*)d_in[6];
    const float* Wcpr = (const float*)d_in[7];
    const float* bcpr = (const float*)d_in[8];
    const float* Wsm  = (const float*)d_in[9];
    const float* bsm  = (const float*)d_in[10];
    float* out = (float*)d_out;
    char* base = (char*)d_ws;   // uses 0x318000 + 4 MB ≈ 7.2 MB of workspace

    static const int grids[7] = {53, 40, 112, 144, 160, 192, 256};
    for (int ph = 0; ph < 7; ++ph)
        phase_k<<<grids[ph], 256, 0, stream>>>(ph, lids, rids, emb, Wih, bih, Wio, bio,
                                               Wcpr, bcpr, Wsm, bsm, out, base);
}

// Round 4
// 209.621 us; speedup vs baseline: 2.2923x; 1.1328x over previous
//
#include <hip/hip_runtime.h>
#include <math.h>

// V=50000 D=128 H=256 C=128 R=7 B=1024 T=128
// Full linear fold: c[b] = sum_{p<16} G^s_p x^s_{126-p}[b] + Gx^s x^s_127[b] (s=L,R) + const
// 7 stream-ordered launches (no cooperative sync, no atomics, no memset):
//   P0: prep(E,Gx,dvec)(25) || stack1{S1,A2}(28)          grid 53
//   P1: stack2{S2,S3,A4}                                   grid 40
//   P2: stack3{S4..7,A8}(64) || fold p0..3 (48)            grid 112
//   P3: stack4{S8..15}(96)   || fold p4..7 (48)            grid 144
//   P4: fold p8..15 (96)     || gemm z=3 tc12..16 (64)     grid 160
//   P5: gemm z=0,1,2 tc0..11                               grid 192
//   P6: tail — reduce 4 cacc slices x 2 sides              grid 256
// R4: latency hiding. Tile bodies double-buffer LDS chunks (barrier -> issue
// next loads -> FMA current -> store next; 1 barrier/chunk). gemm_core<NT>
// register-pipelines B-frags + packed A across tc (named reg sets, 1 barrier/tc).

typedef unsigned short ushortx;
typedef unsigned int uintx;
typedef __attribute__((ext_vector_type(8))) short bhalf8;
typedef __attribute__((ext_vector_type(4))) float f32x4;

#define QT_STRIDE 33024      // 129*256
#define CSL 262144           // 2048*128 floats per slice

__device__ __forceinline__ float bf2f(ushortx u) {
    union { uintx i; float f; } v; v.i = ((uintx)u) << 16; return v.f;
}
__device__ __forceinline__ ushortx f2bf(float f) {
    union { float f; uintx i; } v; v.f = f;
    uintx b = v.i + 0x7fffu + ((v.i >> 16) & 1u);
    return (ushortx)(b >> 16);
}
__device__ __forceinline__ uintx pack2bf(float a, float b) {
    union { float f; uintx i; } va, vb; va.f = a; vb.f = b;
    return ((va.i + 0x8000u) >> 16) | (((vb.i + 0x8000u) >> 16) << 16);
}
__device__ __forceinline__ int b3p_idx(int side, int tc, int j, int n) {
    return ((side * 17 + tc) * 4 + (j >> 5)) * 4096 + ((j >> 3) & 3) * 1024 + n * 8 + (j & 7);
}

struct TileSm { float As[2][16][68]; float Bs[2][16][68]; };      // 17.4 KB
struct GemmSm { ushortx LA[2][32 * 136]; };                       // 17.4 KB
struct TailSm { float dsum[128]; float am[4][128]; float logits[4][8]; float lsev[4]; };
union __align__(16) SMemU { TileSm t; GemmSm g; TailSm x; };

__device__ __forceinline__ void tile_fma(const float (&As)[16][68], const float (&Bs)[16][68],
                                         int tr, int ti, float (&acc)[4][4]) {
#pragma unroll
    for (int kk = 0; kk < 16; ++kk) {
        float4 a4 = *(const float4*)&As[kk][tr * 4];
        float4 b4 = *(const float4*)&Bs[kk][ti * 4];
        float av[4] = {a4.x, a4.y, a4.z, a4.w};
        float bv[4] = {b4.x, b4.y, b4.z, b4.w};
#pragma unroll
        for (int x = 0; x < 4; ++x)
#pragma unroll
            for (int y = 0; y < 4; ++y) acc[x][y] += av[x] * bv[y];
    }
}

// ================= prep body =================
__device__ void prep_body(int b, int tid, TileSm& sm,
                          const float* __restrict__ Wio, const float* __restrict__ bio,
                          const float* __restrict__ Wcpr, const float* __restrict__ bcpr,
                          float* __restrict__ E, ushortx* __restrict__ B3p,
                          float* __restrict__ dvec0) {
    if (b == 24) {
        float* bsh = (float*)sm.As;                  // scratch: 256 floats
        bsh[tid] = bio[tid & 255];
        __syncthreads();
        if (tid < 128) {
            const float* wr = Wcpr + tid * 512;
            float s = bcpr[tid];
#pragma unroll 4
            for (int v = 0; v < 512; v += 4) {
                float4 w = *(const float4*)&wr[v];
                s += w.x * bsh[v & 255] + w.y * bsh[(v + 1) & 255]
                   + w.z * bsh[(v + 2) & 255] + w.w * bsh[(v + 3) & 255];
            }
            dvec0[tid] = s;
        }
        return;
    }
    const int tr = tid >> 4, ti = tid & 15;
    const int r6 = tid >> 6, i63 = tid & 63;
    float acc[4][4] = {{0.f}};
    const int isE = (b < 16);
    const int side = isE ? (b >> 3) : ((b - 16) >> 2);
    const int tile = isE ? (b & 7) : ((b - 16) & 3);
    const int n0 = isE ? ((tile >> 2) * 64) : ((tile >> 1) * 64);
    const int c0 = isE ? ((tile & 3) * 64) : ((tile & 1) * 64);
    const int wofs = isE ? 128 : 0;
    float ra[4], rb[4];
    auto LOAD = [&](int u0) {
#pragma unroll
        for (int q = 0; q < 4; ++q) ra[q] = Wcpr[(n0 + q * 16 + tr) * 512 + side * 256 + u0 + ti];
#pragma unroll
        for (int q = 0; q < 4; ++q) rb[q] = Wio[(u0 + q * 4 + r6) * 384 + wofs + c0 + i63];
    };
    auto STORE = [&](int buf) {
#pragma unroll
        for (int q = 0; q < 4; ++q) sm.As[buf][ti][q * 16 + tr] = ra[q];
#pragma unroll
        for (int q = 0; q < 4; ++q) sm.Bs[buf][q * 4 + r6][i63] = rb[q];
    };
    LOAD(0); STORE(0);
    for (int k = 0; k < 16; ++k) {
        __syncthreads();
        if (k < 15) LOAD((k + 1) * 16);
        tile_fma(sm.As[k & 1], sm.Bs[k & 1], tr, ti, acc);
        if (k < 15) STORE((k + 1) & 1);
    }
    if (isE) {
#pragma unroll
        for (int x = 0; x < 4; ++x) {
            float4 o = make_float4(acc[x][0], acc[x][1], acc[x][2], acc[x][3]);
            *(float4*)&E[side * 32768 + (n0 + tr * 4 + x) * 256 + c0 + ti * 4] = o;
        }
    } else {
#pragma unroll
        for (int x = 0; x < 4; ++x)
#pragma unroll
            for (int y = 0; y < 4; ++y)
                B3p[b3p_idx(side, 16, c0 + ti * 4 + y, n0 + tr * 4 + x)] = f2bf(acc[x][y]);
    }
}

// ================= stack body =================
__device__ void stack_body(int b, int tid, TileSm& sm,
                           const float* __restrict__ Wih, const float* __restrict__ bih,
                           ushortx* __restrict__ QTbf, const float* __restrict__ Ain,
                           float* __restrict__ Aout, int mpow, int count, int lvl1) {
    const int tr = tid >> 4, ti = tid & 15;
    const int r6 = tid >> 6, i63 = tid & 63;
    float acc[4][4] = {{0.f}};
    if (b < count * 12) {
        const int slot = b / 12, rem = b % 12;
        const int i0 = (rem & 3) * 64, r0 = (rem >> 2) * 64;
        float ra[4], rb[4]; float4 ra4;
        const int kk4 = tid >> 4, rq4 = (tid & 15) * 4;
        auto LOAD = [&](int k0) {
            if (slot == 0) {
                int k = k0 + kk4;
                if (r0 < 128) ra4 = *(const float4*)&Wih[k * 384 + r0 + rq4];
                else { ra4.x = (rq4 == 0) ? bih[k] : 0.f; ra4.y = 0.f; ra4.z = 0.f; ra4.w = 0.f; }
            } else {
#pragma unroll
                for (int q = 0; q < 4; ++q) {
                    int r = r0 + q * 16 + tr;
                    ra[q] = (r < 129) ? bf2f(QTbf[slot * QT_STRIDE + r * 256 + k0 + ti]) : 0.f;
                }
            }
#pragma unroll
            for (int q = 0; q < 4; ++q) {
                int i = i0 + q * 16 + tr;
                rb[q] = lvl1 ? Wih[i * 384 + 128 + k0 + ti] : Ain[i * 256 + k0 + ti];
            }
        };
        auto STORE = [&](int buf) {
            if (slot == 0) *(float4*)&sm.As[buf][kk4][rq4] = ra4;
            else {
#pragma unroll
                for (int q = 0; q < 4; ++q) sm.As[buf][ti][q * 16 + tr] = ra[q];
            }
#pragma unroll
            for (int q = 0; q < 4; ++q) sm.Bs[buf][ti][q * 16 + tr] = rb[q];
        };
        LOAD(0); STORE(0);
        for (int k = 0; k < 16; ++k) {
            __syncthreads();
            if (k < 15) LOAD((k + 1) * 16);
            tile_fma(sm.As[k & 1], sm.Bs[k & 1], tr, ti, acc);
            if (k < 15) STORE((k + 1) & 1);
        }
        ushortx* __restrict__ Cdst = QTbf + (mpow + slot) * QT_STRIDE;
#pragma unroll
        for (int x = 0; x < 4; ++x) {
            int r = r0 + tr * 4 + x;
            if (r < 129)
#pragma unroll
                for (int y = 0; y < 4; ++y)
                    Cdst[r * 256 + i0 + ti * 4 + y] = f2bf(acc[x][y]);
        }
    } else {
        const int b2 = b - count * 12;
        const int s0 = (b2 & 3) * 64, i0 = (b2 >> 2) * 64;
        float ra[4], rb[4];
        auto LOAD = [&](int kc) {
#pragma unroll
            for (int q = 0; q < 4; ++q) {
                int i = i0 + q * 16 + tr;
                ra[q] = lvl1 ? Wih[i * 384 + 128 + kc + ti] : Ain[i * 256 + kc + ti];
            }
#pragma unroll
            for (int q = 0; q < 4; ++q) {
                int r = kc + q * 4 + r6;
                rb[q] = lvl1 ? Wih[r * 384 + 128 + s0 + i63] : Ain[r * 256 + s0 + i63];
            }
        };
        auto STORE = [&](int buf) {
#pragma unroll
            for (int q = 0; q < 4; ++q) sm.As[buf][ti][q * 16 + tr] = ra[q];
#pragma unroll
            for (int q = 0; q < 4; ++q) sm.Bs[buf][q * 4 + r6][i63] = rb[q];
        };
        LOAD(0); STORE(0);
        for (int k = 0; k < 16; ++k) {
            __syncthreads();
            if (k < 15) LOAD((k + 1) * 16);
            tile_fma(sm.As[k & 1], sm.Bs[k & 1], tr, ti, acc);
            if (k < 15) STORE((k + 1) & 1);
        }
#pragma unroll
        for (int x = 0; x < 4; ++x) {
            float4 o = make_float4(acc[x][0], acc[x][1], acc[x][2], acc[x][3]);
            *(float4*)&Aout[(i0 + tr * 4 + x) * 256 + s0 + ti * 4] = o;
        }
    }
}

// ================= fold body =================
__device__ void fold_body(int side, int p, int tile, int tid, TileSm& sm,
                          const float* __restrict__ Wih, const float* __restrict__ bih,
                          const ushortx* __restrict__ QTbf, const float* __restrict__ E,
                          ushortx* __restrict__ B3p, float* __restrict__ BiasF) {
    const int n0 = (tile / 3) * 64, r0 = (tile % 3) * 64;
    const int tr = tid >> 4, ti = tid & 15;
    float acc[4][4] = {{0.f}};
    float ra[4], rb[4]; float4 rb4;
    const int kk4 = tid >> 4, rq4 = (tid & 15) * 4;
    auto LOAD = [&](int i0c) {
#pragma unroll
        for (int q = 0; q < 4; ++q)
            ra[q] = E[side * 32768 + (n0 + q * 16 + tr) * 256 + i0c + ti];
        if (p > 0) {
#pragma unroll
            for (int q = 0; q < 4; ++q) {
                int r = r0 + q * 16 + tr;
                rb[q] = (r < 129) ? bf2f(QTbf[p * QT_STRIDE + r * 256 + i0c + ti]) : 0.f;
            }
        } else {
            int i = i0c + kk4;
            if (r0 < 128) rb4 = *(const float4*)&Wih[i * 384 + r0 + rq4];
            else { rb4.x = (rq4 == 0) ? bih[i] : 0.f; rb4.y = 0.f; rb4.z = 0.f; rb4.w = 0.f; }
        }
    };
    auto STORE = [&](int buf) {
#pragma unroll
        for (int q = 0; q < 4; ++q) sm.As[buf][ti][q * 16 + tr] = ra[q];
        if (p > 0) {
#pragma unroll
            for (int q = 0; q < 4; ++q) sm.Bs[buf][ti][q * 16 + tr] = rb[q];
        } else {
            *(float4*)&sm.Bs[buf][kk4][rq4] = rb4;
        }
    };
    LOAD(0); STORE(0);
    for (int k = 0; k < 16; ++k) {
        __syncthreads();
        if (k < 15) LOAD((k + 1) * 16);
        tile_fma(sm.As[k & 1], sm.Bs[k & 1], tr, ti, acc);
        if (k < 15) STORE((k + 1) & 1);
    }
    const int tc = 15 - p;
#pragma unroll
    for (int x = 0; x < 4; ++x) {
        int n = n0 + tr * 4 + x;
#pragma unroll
        for (int y = 0; y < 4; ++y) {
            int r = r0 + ti * 4 + y;
            if (r < 128)
                B3p[b3p_idx(side, tc, r, n)] = f2bf(acc[x][y]);
            else if (r == 128)
                BiasF[(side * 16 + p) * 128 + n] = acc[x][y];
        }
    }
}

// ================= gemm core: register-pipelined over tc =================
template<int NT>
__device__ void gemm_core(int tc_beg, int side, int mb, int tid, GemmSm& sm,
                          const int* __restrict__ idp, const float* __restrict__ emb,
                          const ushortx* __restrict__ B3p, float* __restrict__ cdst) {
    const int lane = tid & 63, wave = tid >> 6;
    const int wn = wave * 32;
    const int r16 = lane & 15, cq = lane >> 4;
    const int arow = tid >> 3, aseg = tid & 7;
    f32x4 acc[2][2] = {};
    bhalf8 bA[4][2], bB[4][2];
    uint4 aA0, aA1, aB0, aB1;
    auto loadB = [&](int q, bhalf8 (&dst)[4][2]) {
        int tc = tc_beg + q;
        const ushortx* __restrict__ bb =
            B3p + (((side * 17 + tc) * 4) << 12) + cq * 1024 + (wn + r16) * 8;
#pragma unroll
        for (int jc = 0; jc < 4; ++jc)
#pragma unroll
            for (int nn = 0; nn < 2; ++nn)
                dst[jc][nn] = *(const bhalf8*)&bb[jc * 4096 + nn * 128];
    };
    auto loadA = [&](int q, uint4& a0, uint4& a1) {
        int tc = tc_beg + q;
        int t = (tc < 16) ? (111 + tc) : 127;
        int id = idp[((mb + arow) << 7) + t];
        const float* __restrict__ as = emb + ((size_t)id << 7) + aseg * 16;
        float4 f0 = *(const float4*)(as);
        float4 f1 = *(const float4*)(as + 4);
        float4 f2 = *(const float4*)(as + 8);
        float4 f3 = *(const float4*)(as + 12);
        a0.x = pack2bf(f0.x, f0.y); a0.y = pack2bf(f0.z, f0.w);
        a0.z = pack2bf(f1.x, f1.y); a0.w = pack2bf(f1.z, f1.w);
        a1.x = pack2bf(f2.x, f2.y); a1.y = pack2bf(f2.z, f2.w);
        a1.z = pack2bf(f3.x, f3.y); a1.w = pack2bf(f3.z, f3.w);
    };
    auto storeA = [&](int buf, const uint4& a0, const uint4& a1) {
        *(uint4*)&sm.LA[buf][arow * 136 + aseg * 16]     = a0;
        *(uint4*)&sm.LA[buf][arow * 136 + aseg * 16 + 8] = a1;
    };
    auto comp = [&](int buf, const bhalf8 (&bq)[4][2]) {
#pragma unroll
        for (int jc = 0; jc < 4; ++jc) {
            bhalf8 af[2];
#pragma unroll
            for (int mm = 0; mm < 2; ++mm)
                af[mm] = *(const bhalf8*)&sm.LA[buf][(mm * 16 + r16) * 136 + jc * 32 + cq * 8];
#pragma unroll
            for (int mm = 0; mm < 2; ++mm)
#pragma unroll
                for (int nn = 0; nn < 2; ++nn)
                    acc[mm][nn] = __builtin_amdgcn_mfma_f32_16x16x32_bf16(af[mm], bq[jc][nn], acc[mm][nn], 0, 0, 0);
        }
    };
    loadB(0, bA); loadA(0, aA0, aA1); storeA(0, aA0, aA1);
#pragma unroll
    for (int q = 0; q < NT; ++q) {
        __syncthreads();
        if (q + 1 < NT) {
            if ((q & 1) == 0) { loadB(q + 1, bB); loadA(q + 1, aB0, aB1); }
            else              { loadB(q + 1, bA); loadA(q + 1, aA0, aA1); }
        }
        if ((q & 1) == 0) comp(q & 1, bA);
        else              comp(q & 1, bB);
        if (q + 1 < NT) {
            if ((q & 1) == 0) storeA((q + 1) & 1, aB0, aB1);
            else              storeA((q + 1) & 1, aA0, aA1);
        }
    }
#pragma unroll
    for (int mm = 0; mm < 2; ++mm)
#pragma unroll
        for (int nn = 0; nn < 2; ++nn)
#pragma unroll
            for (int i = 0; i < 4; ++i) {
                int bq = mb + mm * 16 + cq * 4 + i;
                int n = wn + nn * 16 + r16;
                cdst[bq * 128 + n] = acc[mm][nn][i];
            }
}

// ================= tail body: reduce 4 slices x 2 sides =================
__device__ void tail_body(int b0, int tid, TailSm& sm,
                          const float* __restrict__ caccZ,
                          const float* __restrict__ BiasF, const float* __restrict__ dvec0,
                          const float* __restrict__ Wsm, const float* __restrict__ bsm,
                          float* __restrict__ out) {
    if (tid < 128) {
        float s = dvec0[tid];
#pragma unroll
        for (int q = 0; q < 32; ++q) s += BiasF[q * 128 + tid];
        sm.dsum[tid] = s;
    }
    __syncthreads();
    {
        const int rb = tid >> 6, nn = (tid & 63) * 2;
#pragma unroll
        for (int d = 0; d < 2; ++d) {
            float c = sm.dsum[nn + d];
            const int ofs = (b0 + rb) * 128 + nn + d;
#pragma unroll
            for (int s = 0; s < 4; ++s)
                c += caccZ[s * CSL + ofs] + caccZ[s * CSL + 131072 + ofs];
            sm.am[rb][nn + d] = (c >= 0.f) ? c : 0.01f * c;
        }
    }
    __syncthreads();
    if (tid < 28) {
        int rb = tid / 7, r = tid % 7;
        float s = bsm[r];
        for (int q = 0; q < 128; ++q) s += sm.am[rb][q] * Wsm[r * 128 + q];
        sm.logits[rb][r] = s;
    }
    __syncthreads();
    if (tid < 4) {
        float mx = sm.logits[tid][0];
        for (int r = 1; r < 7; ++r) mx = fmaxf(mx, sm.logits[tid][r]);
        float se = 0.f;
        for (int r = 0; r < 7; ++r) se += expf(sm.logits[tid][r] - mx);
        sm.lsev[tid] = mx + logf(se);
    }
    __syncthreads();
    if (tid < 28) {
        int rb = tid / 7, r = tid % 7;
        out[(b0 + rb) * 7 + r] = sm.logits[rb][r] - sm.lsev[rb];
    }
}

// ================= phase kernel =================
__global__ __launch_bounds__(256) void phase_k(int ph, const int* lids, const int* rids,
                                               const float* emb, const float* Wih,
                                               const float* bih, const float* Wio,
                                               const float* bio, const float* Wcpr,
                                               const float* bcpr, const float* Wsm,
                                               const float* bsm, float* out, char* base) {
    __shared__ SMemU sm;
    const int bx = blockIdx.x, tid = threadIdx.x;
    ushortx* QTbf  = (ushortx*)(base);                 // 16*33024*2
    ushortx* B3p   = (ushortx*)(base + 0x102000);      // 557056*2
    float*   BiasF = (float*)  (base + 0x212000);      // 2*16*128*4
    float*   E     = (float*)  (base + 0x216000);      // 2*128*256*4
    float*   dvec0 = (float*)  (base + 0x256000);      // 512
    float*   A2    = (float*)  (base + 0x258000);
    float*   A4    = (float*)  (base + 0x298000);
    float*   A8    = (float*)  (base + 0x2D8000);
    float*   caccZ = (float*)  (base + 0x318000);      // 4 * 2048*128*4 = 4 MB
    switch (ph) {
    case 0:
        if (bx < 25) prep_body(bx, tid, sm.t, Wio, bio, Wcpr, bcpr, E, B3p, dvec0);
        else if (bx < 53) stack_body(bx - 25, tid, sm.t, Wih, bih, QTbf, nullptr, A2, 1, 1, 1);
        break;
    case 1:
        if (bx < 40) stack_body(bx, tid, sm.t, Wih, bih, QTbf, A2, A4, 2, 2, 0);
        break;
    case 2:
        if (bx < 64) stack_body(bx, tid, sm.t, Wih, bih, QTbf, A4, A8, 4, 4, 0);
        else if (bx < 112) {
            int pp = bx - 64;
            fold_body(pp / 24, (pp % 24) / 6, pp % 6, tid, sm.t, Wih, bih, QTbf, E, B3p, BiasF);
        }
        break;
    case 3:
        if (bx < 96) stack_body(bx, tid, sm.t, Wih, bih, QTbf, A8, nullptr, 8, 8, 0);
        else if (bx < 144) {
            int pp = bx - 96;
            fold_body(pp / 24, 4 + (pp % 24) / 6, pp % 6, tid, sm.t, Wih, bih, QTbf, E, B3p, BiasF);
        }
        break;
    case 4:
        if (bx < 96) {
            fold_body(bx / 48, 8 + (bx % 48) / 6, bx % 6, tid, sm.t, Wih, bih, QTbf, E, B3p, BiasF);
        } else if (bx < 160) {
            int g = bx - 96, m0 = g * 32, side = (m0 >= 1024);
            gemm_core<5>(12, side, m0 & 1023, tid, sm.g, side ? rids : lids, emb, B3p,
                         caccZ + (size_t)3 * CSL + side * 131072);
        }
        break;
    case 5:
        if (bx < 192) {
            int z = bx % 3, m0 = (bx / 3) * 32, side = (m0 >= 1024);
            gemm_core<4>(z * 4, side, m0 & 1023, tid, sm.g, side ? rids : lids, emb, B3p,
                         caccZ + (size_t)z * CSL + side * 131072);
        }
        break;
    case 6:
        tail_body(bx * 4, tid, sm.x, caccZ, BiasF, dvec0, Wsm, bsm, out);
        break;
    }
}

extern "C" void kernel_launch(void* const* d_in, const int* in_sizes, int n_in,
                              void* d_out, int out_size, void* d_ws, size_t ws_size,
                              hipStream_t stream) {
    const int*   lids = (const int*)  d_in[0];
    const int*   rids = (const int*)  d_in[1];
    const float* emb  = (const float*)d_in[2];
    const float* Wih  = (const float*)d_in[3];
    const float* bih  = (const float*)d_in[4];
    const float* Wio  = (const float*)d_in[5];
    const float* bio  = (const float*)d_in[6];
    const float* Wcpr = (const float*)d_in[7];
    const float* bcpr = (const float*)d_in[8];
    const float* Wsm  = (const float*)d_in[9];
    const float* bsm  = (const float*)d_in[10];
    float* out = (float*)d_out;
    char* base = (char*)d_ws;   // uses 0x318000 + 4 MB ≈ 7.2 MB of workspace

    static const int grids[7] = {53, 40, 112, 144, 160, 192, 256};
    for (int ph = 0; ph < 7; ++ph)
        phase_k<<<grids[ph], 256, 0, stream>>>(ph, lids, rids, emb, Wih, bih, Wio, bio,
                                               Wcpr, bcpr, Wsm, bsm, out, base);
}